// Round 2
// baseline (1496.865 us; speedup 1.0000x reference)
//
#include <hip/hip_runtime.h>

#define NROUTES 1152
#define NCAPS   10
#define INCH    8
#define OUTCH   16
#define NBATCH  512
#define NITER   3
#define TPB     384   // 6 waves
#define RPT     3     // routes per thread: 384*3 = 1152
#define NWAVES  (TPB / 64)

__global__ __launch_bounds__(TPB, 4)   // force <=128 VGPR bin, 4 waves/SIMD
void caps_route_kernel(const float* __restrict__ X,     // (R, B, I)
                       const float* __restrict__ W,     // (R, C, O, I)
                       float* __restrict__ OUT)         // (B, C, O)
{
    const int t    = threadIdx.x;
    const int wid  = t >> 6;
    const int lane = t & 63;
    const int c    = blockIdx.x / NBATCH;     // c-major: blocks sharing c are contiguous
    const int b    = blockIdx.x % NBATCH;

    __shared__ float red[NWAVES][20];   // per-wave partials: [0..15]=S, [16]=Z
    __shared__ float fin[20];           // reduced totals
    __shared__ float redmax[NWAVES];

    float u[RPT][OUTCH];   // u_hat fragments (48 VGPRs)
    float bij[RPT];        // routing logits
    float vjv[OUTCH];      // partial S during reduce; v after squash

    // ---------------- u_hat = W[r,c] @ x[r,b] ----------------
    #pragma unroll
    for (int j = 0; j < RPT; ++j) {
        const int r = t * RPT + j;
        const float* xp = X + ((size_t)r * NBATCH + b) * INCH;
        float4 a0 = *reinterpret_cast<const float4*>(xp);
        float4 a1 = *reinterpret_cast<const float4*>(xp + 4);
        const float xv[INCH] = { a0.x, a0.y, a0.z, a0.w, a1.x, a1.y, a1.z, a1.w };
        const float* wp = W + ((size_t)r * NCAPS + c) * (OUTCH * INCH);
        #pragma unroll
        for (int o = 0; o < OUTCH; ++o) {
            float4 w0 = *reinterpret_cast<const float4*>(wp + o * INCH);
            float4 w1 = *reinterpret_cast<const float4*>(wp + o * INCH + 4);
            float acc = w0.x * xv[0];
            acc = fmaf(w0.y, xv[1], acc);
            acc = fmaf(w0.z, xv[2], acc);
            acc = fmaf(w0.w, xv[3], acc);
            acc = fmaf(w1.x, xv[4], acc);
            acc = fmaf(w1.y, xv[5], acc);
            acc = fmaf(w1.z, xv[6], acc);
            acc = fmaf(w1.w, xv[7], acc);
            u[j][o] = acc;
        }
    }

    #pragma unroll
    for (int j = 0; j < RPT; ++j) bij[j] = 0.0f;

    // ---------------- dynamic routing ----------------
    for (int it = 0; it < NITER; ++it) {
        // ---- block max of bij (stable softmax) ----
        float mx = bij[0];
        #pragma unroll
        for (int j = 1; j < RPT; ++j) mx = fmaxf(mx, bij[j]);
        #pragma unroll
        for (int sh = 1; sh <= 32; sh <<= 1)
            mx = fmaxf(mx, __shfl_xor(mx, sh));
        if (lane == 0) redmax[wid] = mx;
        __syncthreads();
        {
            float m = redmax[0];
            #pragma unroll
            for (int w = 1; w < NWAVES; ++w) m = fmaxf(m, redmax[w]);
            mx = m;
        }

        // ---- e = exp(b - max); partial Z and S = sum e*u ----
        float Z = 0.0f;
        #pragma unroll
        for (int o = 0; o < OUTCH; ++o) vjv[o] = 0.0f;
        #pragma unroll
        for (int j = 0; j < RPT; ++j) {
            float ev = __expf(bij[j] - mx);
            Z += ev;
            #pragma unroll
            for (int o = 0; o < OUTCH; ++o)
                vjv[o] = fmaf(ev, u[j][o], vjv[o]);
        }

        // ---- wave butterfly reduce of {S[16], Z} ----
        #pragma unroll
        for (int sh = 1; sh <= 32; sh <<= 1) {
            Z += __shfl_xor(Z, sh);
            #pragma unroll
            for (int o = 0; o < OUTCH; ++o)
                vjv[o] += __shfl_xor(vjv[o], sh);
        }
        if (lane == 0) {
            #pragma unroll
            for (int o = 0; o < OUTCH; ++o) red[wid][o] = vjv[o];
            red[wid][16] = Z;
        }
        __syncthreads();

        // ---- cross-wave reduce: threads 0..16 each own one value ----
        if (t < 17) {
            float s = red[0][t];
            #pragma unroll
            for (int w = 1; w < NWAVES; ++w) s += red[w][t];
            fin[t] = s;
        }
        __syncthreads();

        // ---- squash (every thread redundantly; broadcast from LDS) ----
        {
            float4 s0 = *reinterpret_cast<const float4*>(&fin[0]);
            float4 s1 = *reinterpret_cast<const float4*>(&fin[4]);
            float4 s2 = *reinterpret_cast<const float4*>(&fin[8]);
            float4 s3 = *reinterpret_cast<const float4*>(&fin[12]);
            float Zt  = fin[16];
            float rZ  = 1.0f / Zt;
            float sv[OUTCH] = { s0.x, s0.y, s0.z, s0.w,
                                s1.x, s1.y, s1.z, s1.w,
                                s2.x, s2.y, s2.z, s2.w,
                                s3.x, s3.y, s3.z, s3.w };
            float n2 = 0.0f;
            #pragma unroll
            for (int o = 0; o < OUTCH; ++o) {
                sv[o] *= rZ;
                n2 = fmaf(sv[o], sv[o], n2);
            }
            float sc = sqrtf(n2) / (1.0f + n2);
            #pragma unroll
            for (int o = 0; o < OUTCH; ++o) vjv[o] = sv[o] * sc;
        }

        // ---- logit update: b += <u, v>  (skip on last iter) ----
        if (it < NITER - 1) {
            #pragma unroll
            for (int j = 0; j < RPT; ++j) {
                float d = 0.0f;
                #pragma unroll
                for (int o = 0; o < OUTCH; ++o)
                    d = fmaf(u[j][o], vjv[o], d);
                bij[j] += d;
            }
        }
        __syncthreads();   // protect red/redmax/fin reuse next iteration
    }

    // ---------------- write v: out[b, c, :] ----------------
    if (t == 0) {
        float* op = OUT + ((size_t)b * NCAPS + c) * OUTCH;
        #pragma unroll
        for (int o = 0; o < OUTCH; o += 4)
            *reinterpret_cast<float4*>(op + o) =
                make_float4(vjv[o], vjv[o + 1], vjv[o + 2], vjv[o + 3]);
    }
}

extern "C" void kernel_launch(void* const* d_in, const int* in_sizes, int n_in,
                              void* d_out, int out_size, void* d_ws, size_t ws_size,
                              hipStream_t stream) {
    const float* X = (const float*)d_in[0];            // (1152, 512, 8)
    const float* W = (const float*)d_in[1];            // (1152, 10, 16, 8)
    float* OUT     = (float*)d_out;                    // (512, 10, 16)
    dim3 grid(NCAPS * NBATCH);                         // 5120 workgroups, c-major
    caps_route_kernel<<<grid, dim3(TPB), 0, stream>>>(X, W, OUT);
}